// Round 2
// baseline (251.820 us; speedup 1.0000x reference)
//
#include <hip/hip_runtime.h>
#include <math.h>

#define BATCH 8
#define CH    256
#define H     128
#define W     128
#define HW    (H * W)          // 16384
#define OH    65
#define OW    65
#define NPIX  (OH * OW)        // 4225
#define TPB   512
#define WAVES 8
#define CPW   (CH / WAVES)     // 32 channels per wave
#define TASKS (CPW * OW)       // 2080 flattened (channel, ow) tasks per wave
#define ITERS ((TASKS + 63) / 64)  // 33

// Fused kernel: one block = one output row (oh) of one image (b), all channels.
// Phase 1: stream the 3 (clamped) input rows across all 256 channels, accumulate
//          per-pixel channel sum-of-squares (wave-partial in regs, LDS tree).
// Phase 2: 65 softmax weight sets -> LDS; pool re-reads the strip (L1/L2-hot).
// x is read ONCE from HBM (plus even-row halo shared with the adjacent block,
// which is temporally local -> L2/L3). No norm workspace traffic at all.
__global__ __launch_bounds__(TPB) void fused_kernel(const float* __restrict__ x,
                                                    float* __restrict__ out) {
    const int bx   = blockIdx.x;
    const int b    = bx / OH;
    const int oh   = bx - b * OH;
    const int tid  = threadIdx.x;
    const int lane = tid & 63;
    const int wv   = tid >> 6;

    // clamped input rows for this output row (block-uniform -> SGPRs)
    int  rowc[3];
    bool rv[3];
    #pragma unroll
    for (int r = 0; r < 3; ++r) {
        int ih = oh * 2 + r - 2;
        rv[r]   = (unsigned)ih < (unsigned)H;
        rowc[r] = ih < 0 ? 0 : (ih > H - 1 ? H - 1 : ih);
    }

    __shared__ float part[WAVES][3][W];  // 12 KB: per-wave per-row partial sums
    __shared__ float nrm[3][W];          // 1.5 KB: channel L2 norms of the strip
    __shared__ float wls[OH][11];        // 2.9 KB: 9 softmax weights (stride 11 = odd)

    // ---- phase 1: sum of squares over this wave's 32 channels ----
    const float* xw = x + (size_t)(b * CH + wv * CPW) * HW;
    float2 a0 = {0.f, 0.f}, a1 = {0.f, 0.f}, a2 = {0.f, 0.f};
    #pragma unroll 4
    for (int c = 0; c < CPW; ++c) {
        const float* xp = xw + (size_t)c * HW;
        float2 v0 = *(const float2*)(xp + rowc[0] * W + 2 * lane);
        float2 v1 = *(const float2*)(xp + rowc[1] * W + 2 * lane);
        float2 v2 = *(const float2*)(xp + rowc[2] * W + 2 * lane);
        a0.x += v0.x * v0.x; a0.y += v0.y * v0.y;
        a1.x += v1.x * v1.x; a1.y += v1.y * v1.y;
        a2.x += v2.x * v2.x; a2.y += v2.y * v2.y;
    }
    *(float2*)&part[wv][0][2 * lane] = a0;
    *(float2*)&part[wv][1][2 * lane] = a1;
    *(float2*)&part[wv][2][2 * lane] = a2;
    __syncthreads();

    // ---- cross-wave reduce -> norms (384 threads, conflict-free: addr = col) ----
    if (tid < 3 * W) {
        int r = tid >> 7, col = tid & (W - 1);
        float s = 0.f;
        #pragma unroll
        for (int w = 0; w < WAVES; ++w) s += part[w][r][col];
        nrm[r][col] = sqrtf(s);
    }
    __syncthreads();

    // ---- softmax weights for the 65 output columns (same math as verified K2) ----
    if (tid < OH) {
        const int ow  = tid;
        const int iw0 = ow * 2 - 2;
        float nv[9];
        bool  val[9];
        float m = 0.0f;
        #pragma unroll
        for (int kh = 0; kh < 3; ++kh) {
            bool vh = rv[kh];
            #pragma unroll
            for (int kw = 0; kw < 3; ++kw) {
                int iw = iw0 + kw;
                int k  = kh * 3 + kw;
                bool v = vh && ((unsigned)iw < (unsigned)W);
                val[k] = v;
                nv[k]  = v ? nrm[kh][iw] : 0.0f;
                m = fmaxf(m, nv[k]);
            }
        }
        float denom = 0.0f, wt[9];
        #pragma unroll
        for (int k = 0; k < 9; ++k) {
            float e = __expf(nv[k] - m);
            denom += e;
            wt[k] = val[k] ? e : 0.0f;
        }
        float inv = 1.0f / denom;
        #pragma unroll
        for (int k = 0; k < 9; ++k) wls[ow][k] = wt[k] * inv;
    }
    __syncthreads();

    // ---- phase 2: pool this wave's 32 channels (strip is L1/L2-hot) ----
    // flattened tasks: id -> (c = id/65, ow = id%65); avoids the odd-width
    // lane-63 divergence. Stores: <=2 contiguous runs per wave instruction.
    float* ob = out + (size_t)(b * CH + wv * CPW) * NPIX + (size_t)oh * OW;
    #pragma unroll 2
    for (int it = 0; it < ITERS; ++it) {
        int id = it * 64 + lane;
        if (id < TASKS) {
            int c  = id / OW;              // magic-mul, no divide
            int ow = id - c * OW;
            int iw0 = ow * 2 - 2;
            int iwa = iw0 < 0 ? 0 : iw0;                       // even -> aligned float2
            int iwc = (iw0 + 2) > (W - 1) ? (W - 1) : (iw0 + 2);
            float w0 = wls[ow][0], w1 = wls[ow][1], w2 = wls[ow][2];
            float w3 = wls[ow][3], w4 = wls[ow][4], w5 = wls[ow][5];
            float w6 = wls[ow][6], w7 = wls[ow][7], w8 = wls[ow][8];
            const float* xc = xw + (size_t)c * HW;
            const float* r0 = xc + rowc[0] * W;
            const float* r1 = xc + rowc[1] * W;
            const float* r2 = xc + rowc[2] * W;
            float2 p0 = *(const float2*)(r0 + iwa);
            float2 p1 = *(const float2*)(r1 + iwa);
            float2 p2 = *(const float2*)(r2 + iwa);
            float  s0 = r0[iwc], s1 = r1[iwc], s2 = r2[iwc];
            float acc = w0 * p0.x + w1 * p0.y + w2 * s0
                      + w3 * p1.x + w4 * p1.y + w5 * s1
                      + w6 * p2.x + w7 * p2.y + w8 * s2;
            ob[(size_t)c * NPIX + ow] = acc;
        }
    }
}

extern "C" void kernel_launch(void* const* d_in, const int* in_sizes, int n_in,
                              void* d_out, int out_size, void* d_ws, size_t ws_size,
                              hipStream_t stream) {
    const float* x = (const float*)d_in[0];
    float* out = (float*)d_out;
    (void)d_ws; (void)ws_size;
    // one block per (image, output row): 8 * 65 = 520 blocks, 512 threads
    fused_kernel<<<BATCH * OH, TPB, 0, stream>>>(x, out);
}

// Round 3
// 215.304 us; speedup vs baseline: 1.1696x; 1.1696x over previous
//
#include <hip/hip_runtime.h>
#include <math.h>

#define BATCH 8
#define CH    256
#define H     128
#define W     128
#define HW    (H * W)          // 16384
#define OH    65
#define OW    65
#define NPIX  (OH * OW)        // 4225
#define TPB   512
#define WAVES 8
#define CPW   (CH / WAVES)     // 32 channels per wave

// Fully-fused, register-resident kernel. One block = one output row (oh) of one
// image (b), all 256 channels. Lane l of each wave owns input columns (2l, 2l+1)
// of the 3 (clamped) window rows for its wave's 32 channels:
//   phase 1: load 96 float2 (independent -> deep ILP, HBM-saturating), keep ALL
//            values in registers, accumulate channel sum-of-squares.
//   reduce:  LDS tree across waves -> per-column strip norms -> 65 softmax
//            weight sets (block-uniform, computed once).
//   phase 2: pure-VALU pooling from the SAME registers. out[ow] = T_ow + S_{ow-1}:
//            lane l computes T_l (kw=2 term: x[2l]=vx) and S_l (kw=0,1 terms for
//            ow=l+1: x[2l]=vx, x[2l+1]=vy); one __shfl_up combines. out[64]=S_63
//            (its kw=2 weight is OOB-zero). x is read from HBM exactly once.
__global__ __launch_bounds__(TPB) void fused_kernel(const float* __restrict__ x,
                                                    float* __restrict__ out) {
    // XCD-chunked mapping: dispatch round-robins (bid % 8) across the 8 XCDs,
    // so b = bid & 7 pins each image to one XCD; consecutive oh blocks are
    // temporally adjacent there -> even-row halo served by that XCD's L2.
    const int b    = blockIdx.x & 7;
    const int oh   = blockIdx.x >> 3;
    const int tid  = threadIdx.x;
    const int lane = tid & 63;
    const int wv   = tid >> 6;

    // clamped input rows for this output row (block-uniform)
    int  rowc[3];
    bool rv[3];
    #pragma unroll
    for (int r = 0; r < 3; ++r) {
        int ih = oh * 2 + r - 2;
        rv[r]   = (unsigned)ih < (unsigned)H;
        rowc[r] = ih < 0 ? 0 : (ih > H - 1 ? H - 1 : ih);
    }

    __shared__ float part[WAVES][3][W];  // 12 KB  per-wave per-row partial SSQ
    __shared__ float nrm[3][W];          // 1.5 KB strip channel-norms
    __shared__ float wls[OH][9];         // 2.3 KB softmax weights (stride 9 = odd)

    // ---- phase 1: load strip into registers, accumulate sum of squares ----
    const float2* xw2 = (const float2*)x + (size_t)(b * CH + wv * CPW) * (HW / 2);
    const int base0 = rowc[0] * (W / 2) + lane;
    const int base1 = rowc[1] * (W / 2) + lane;
    const int base2 = rowc[2] * (W / 2) + lane;

    float2 xv[CPW][3];                   // 192 VGPRs: the entire strip slice
    float2 a0 = {0.f, 0.f}, a1 = {0.f, 0.f}, a2 = {0.f, 0.f};
    #pragma unroll
    for (int c = 0; c < CPW; ++c) {
        const size_t cb = (size_t)c * (HW / 2);
        xv[c][0] = xw2[cb + base0];
        xv[c][1] = xw2[cb + base1];
        xv[c][2] = xw2[cb + base2];
    }
    #pragma unroll
    for (int c = 0; c < CPW; ++c) {
        a0.x += xv[c][0].x * xv[c][0].x; a0.y += xv[c][0].y * xv[c][0].y;
        a1.x += xv[c][1].x * xv[c][1].x; a1.y += xv[c][1].y * xv[c][1].y;
        a2.x += xv[c][2].x * xv[c][2].x; a2.y += xv[c][2].y * xv[c][2].y;
    }
    *(float2*)&part[wv][0][2 * lane] = a0;
    *(float2*)&part[wv][1][2 * lane] = a1;
    *(float2*)&part[wv][2][2 * lane] = a2;
    __syncthreads();

    // ---- cross-wave reduce -> norms (384 threads, stride-1 -> conflict-free) ----
    if (tid < 3 * W) {
        int r = tid >> 7, col = tid & (W - 1);
        float s = 0.f;
        #pragma unroll
        for (int w = 0; w < WAVES; ++w) s += part[w][r][col];
        nrm[r][col] = sqrtf(s);
    }
    __syncthreads();

    // ---- softmax weights for the 65 output columns (same math as verified) ----
    if (tid < OH) {
        const int ow  = tid;
        const int iw0 = ow * 2 - 2;
        float nv[9];
        bool  val[9];
        float m = 0.0f;
        #pragma unroll
        for (int kh = 0; kh < 3; ++kh) {
            bool vh = rv[kh];
            #pragma unroll
            for (int kw = 0; kw < 3; ++kw) {
                int iw = iw0 + kw;
                int k  = kh * 3 + kw;
                bool v = vh && ((unsigned)iw < (unsigned)W);
                val[k] = v;
                nv[k]  = v ? nrm[kh][iw] : 0.0f;
                m = fmaxf(m, nv[k]);
            }
        }
        float denom = 0.0f, wt[9];
        #pragma unroll
        for (int k = 0; k < 9; ++k) {
            float e = __expf(nv[k] - m);
            denom += e;
            wt[k] = val[k] ? e : 0.0f;
        }
        float inv = 1.0f / denom;
        #pragma unroll
        for (int k = 0; k < 9; ++k) wls[ow][k] = wt[k] * inv;
    }
    __syncthreads();

    // ---- phase 2: pool straight from registers (no global re-read) ----
    // lane l: T uses own-ow (l) kw=2 weights; S uses ow=l+1 kw=0,1 weights.
    // stride-9 LDS rows -> conflict-free broadcast-ish reads, done ONCE.
    const float wA0 = wls[lane][2], wA1 = wls[lane][5], wA2 = wls[lane][8];
    const float wB0 = wls[lane + 1][0], wC0 = wls[lane + 1][1];
    const float wB1 = wls[lane + 1][3], wC1 = wls[lane + 1][4];
    const float wB2 = wls[lane + 1][6], wC2 = wls[lane + 1][7];

    float* ob = out + (size_t)(b * CH + wv * CPW) * NPIX + (size_t)oh * OW;
    #pragma unroll
    for (int c = 0; c < CPW; ++c) {
        const float vx0 = xv[c][0].x, vy0 = xv[c][0].y;
        const float vx1 = xv[c][1].x, vy1 = xv[c][1].y;
        const float vx2 = xv[c][2].x, vy2 = xv[c][2].y;
        float S = wB0 * vx0 + wC0 * vy0
                + wB1 * vx1 + wC1 * vy1
                + wB2 * vx2 + wC2 * vy2;          // -> out[lane+1]
        float T = wA0 * vx0 + wA1 * vx1 + wA2 * vx2;  // -> out[lane]
        float Sp = __shfl_up(S, 1);
        float res = (lane == 0) ? T : T + Sp;
        ob[(size_t)c * NPIX + lane] = res;            // coalesced 64-float run
        if (lane == 63) ob[(size_t)c * NPIX + 64] = S; // ow=64: kw=2 weight is 0
    }
}

extern "C" void kernel_launch(void* const* d_in, const int* in_sizes, int n_in,
                              void* d_out, int out_size, void* d_ws, size_t ws_size,
                              hipStream_t stream) {
    const float* x = (const float*)d_in[0];
    float* out = (float*)d_out;
    (void)d_ws; (void)ws_size;
    // 8 images * 65 output rows = 520 blocks (divisible by 8 -> clean XCD chunks)
    fused_kernel<<<BATCH * OH, TPB, 0, stream>>>(x, out);
}